// Round 1
// baseline (486.367 us; speedup 1.0000x reference)
//
#include <hip/hip_runtime.h>
#include <hip/hip_bf16.h>

typedef __attribute__((ext_vector_type(8))) short short8;
typedef __attribute__((ext_vector_type(4))) short short4v;
typedef __attribute__((ext_vector_type(4))) float floatx4;

#define S_LEN 4096
#define HIDDEN 2304
#define NHEADS 8
#define NKVH 4
#define HDIM 256
#define SWIN 2048

static __device__ __forceinline__ short bf16bits(float x) {
    __hip_bfloat16 h = __float2bfloat16(x);
    return __builtin_bit_cast(short, h);
}
static __device__ __forceinline__ float bits2f(short b) {
    return __bfloat162float(__builtin_bit_cast(__hip_bfloat16, b));
}

static __device__ __forceinline__ void gload_lds16(const short* g, short* l) {
    __builtin_amdgcn_global_load_lds((const __attribute__((address_space(1))) void*)g,
                                     (__attribute__((address_space(3))) void*)l,
                                     16, 0, 0);
}

// ---------------- cast fp32 -> bf16 (4 elems/thread) ----------------
__global__ __launch_bounds__(256) void cast_f32_bf16(const float* __restrict__ in,
                                                     short* __restrict__ out, int n4) {
    int i = blockIdx.x * 256 + threadIdx.x;
    if (i >= n4) return;
    float4 v = ((const float4*)in)[i];
    short4v o;
    o.x = bf16bits(v.x); o.y = bf16bits(v.y); o.z = bf16bits(v.z); o.w = bf16bits(v.w);
    ((short4v*)out)[i] = o;
}

// ---------------- fused W cast: [Wq;Wk;Wv] -> one bf16 [4096][2304] ----------------
__global__ __launch_bounds__(256) void cast_wqkv(const float* __restrict__ Wq,
                                                 const float* __restrict__ Wk,
                                                 const float* __restrict__ Wv,
                                                 short* __restrict__ dst) {
    const int NQ4 = 1179648, NK4 = 589824;      // float4 counts
    int i = blockIdx.x * 256 + threadIdx.x;     // 0 .. 2359295
    const float4* src;
    if (i < NQ4)            src = (const float4*)Wq + i;
    else if (i < NQ4 + NK4) src = (const float4*)Wk + (i - NQ4);
    else                    src = (const float4*)Wv + (i - NQ4 - NK4);
    float4 v = *src;
    short4v o;
    o.x = bf16bits(v.x); o.y = bf16bits(v.y); o.z = bf16bits(v.z); o.w = bf16bits(v.w);
    ((short4v*)dst)[i] = o;
}

// ---------------- generic GEMM (m97-style): C[M,N] = A[M,K]*B[N,K]^T ----------------
// MODE 0: bf16 row-major; MODE 2: fp32 row-major.
template<int MODE>
__global__ __launch_bounds__(256) void gemm_lds(const short* __restrict__ A,
                                                const short* __restrict__ B,
                                                void* __restrict__ Cp,
                                                int M, int N, int K, int ldc)
{
    __shared__ __align__(16) short lA[128 * 32];
    __shared__ __align__(16) short lB[128 * 32];
    int tid  = threadIdx.x;
    int lane = tid & 63;
    int wave = tid >> 6;
    int col  = lane & 15;
    int quad = lane >> 4;
    int m_base = blockIdx.y * 128;
    int n_base = blockIdx.x * 128;
    int wm = (wave >> 1) * 64;
    int wn = (wave & 1) * 64;

    int srow = wave * 32 + (lane >> 2);
    int scol = (lane & 3) * 8;
    const short* gA0 = A + (size_t)(m_base + srow) * K + scol;
    const short* gA1 = gA0 + (size_t)16 * K;
    const short* gB0 = B + (size_t)(n_base + srow) * K + scol;
    const short* gB1 = gB0 + (size_t)16 * K;
    short* lA0 = lA + wave * 1024;
    short* lB0 = lB + wave * 1024;

    floatx4 acc[4][4] = {};

    for (int k0 = 0; k0 < K; k0 += 32) {
        __syncthreads();
        gload_lds16(gA0 + k0, lA0);
        gload_lds16(gA1 + k0, lA0 + 512);
        gload_lds16(gB0 + k0, lB0);
        gload_lds16(gB1 + k0, lB0 + 512);
        __syncthreads();

        short8 af[4], bf[4];
        #pragma unroll
        for (int t = 0; t < 4; ++t) {
            af[t] = *(const short8*)(lA + (wm + t*16 + col) * 32 + quad * 8);
            bf[t] = *(const short8*)(lB + (wn + t*16 + col) * 32 + quad * 8);
        }
        #pragma unroll
        for (int mt = 0; mt < 4; ++mt)
            #pragma unroll
            for (int nt = 0; nt < 4; ++nt)
                acc[mt][nt] = __builtin_amdgcn_mfma_f32_16x16x32_bf16(af[mt], bf[nt], acc[mt][nt], 0, 0, 0);
    }

    #pragma unroll
    for (int mt = 0; mt < 4; ++mt) {
        #pragma unroll
        for (int nt = 0; nt < 4; ++nt) {
            int n  = n_base + wn + nt*16 + col;
            int m0 = m_base + wm + mt*16 + quad*4;
            if (MODE == 0) {
                short* C = (short*)Cp;
                #pragma unroll
                for (int r = 0; r < 4; ++r)
                    C[(size_t)(m0 + r) * ldc + n] = bf16bits(acc[mt][nt][r]);
            } else {
                float* C = (float*)Cp;
                #pragma unroll
                for (int r = 0; r < 4; ++r)
                    C[(size_t)(m0 + r) * ldc + n] = acc[mt][nt][r];
            }
        }
    }
}

// ---------------- fused QKV GEMM: A=Xb[4096][2304], B=Wqkvb[4096][2304] ----------------
// n in [0,3072): QKV[m][n] bf16 row-major (ld 4096).  Q cols 0..2047, K cols 2048..3071.
// n in [3072,4096): Vt[n-3072][m] transposed (ld 4096).
__global__ __launch_bounds__(256) void gemm_qkv(const short* __restrict__ A,
                                                const short* __restrict__ B,
                                                short* __restrict__ QKV,
                                                short* __restrict__ Vt)
{
    __shared__ __align__(16) short lA[128 * 32];
    __shared__ __align__(16) short lB[128 * 32];
    const int K = HIDDEN;
    int tid  = threadIdx.x;
    int lane = tid & 63;
    int wave = tid >> 6;
    int col  = lane & 15;
    int quad = lane >> 4;
    int m_base = blockIdx.y * 128;
    int n_base = blockIdx.x * 128;
    int wm = (wave >> 1) * 64;
    int wn = (wave & 1) * 64;

    int srow = wave * 32 + (lane >> 2);
    int scol = (lane & 3) * 8;
    const short* gA0 = A + (size_t)(m_base + srow) * K + scol;
    const short* gA1 = gA0 + (size_t)16 * K;
    const short* gB0 = B + (size_t)(n_base + srow) * K + scol;
    const short* gB1 = gB0 + (size_t)16 * K;
    short* lA0 = lA + wave * 1024;
    short* lB0 = lB + wave * 1024;

    floatx4 acc[4][4] = {};

    for (int k0 = 0; k0 < K; k0 += 32) {
        __syncthreads();
        gload_lds16(gA0 + k0, lA0);
        gload_lds16(gA1 + k0, lA0 + 512);
        gload_lds16(gB0 + k0, lB0);
        gload_lds16(gB1 + k0, lB0 + 512);
        __syncthreads();

        short8 af[4], bf[4];
        #pragma unroll
        for (int t = 0; t < 4; ++t) {
            af[t] = *(const short8*)(lA + (wm + t*16 + col) * 32 + quad * 8);
            bf[t] = *(const short8*)(lB + (wn + t*16 + col) * 32 + quad * 8);
        }
        #pragma unroll
        for (int mt = 0; mt < 4; ++mt)
            #pragma unroll
            for (int nt = 0; nt < 4; ++nt)
                acc[mt][nt] = __builtin_amdgcn_mfma_f32_16x16x32_bf16(af[mt], bf[nt], acc[mt][nt], 0, 0, 0);
    }

    #pragma unroll
    for (int mt = 0; mt < 4; ++mt) {
        #pragma unroll
        for (int nt = 0; nt < 4; ++nt) {
            int n  = n_base + wn + nt*16 + col;
            int m0 = m_base + wm + mt*16 + quad*4;
            if (n_base + wn + nt*16 < 3072) {
                #pragma unroll
                for (int r = 0; r < 4; ++r)
                    QKV[(size_t)(m0 + r) * 4096 + n] = bf16bits(acc[mt][nt][r]);
            } else {
                short4v v;
                v.x = bf16bits(acc[mt][nt][0]);
                v.y = bf16bits(acc[mt][nt][1]);
                v.z = bf16bits(acc[mt][nt][2]);
                v.w = bf16bits(acc[mt][nt][3]);
                *(short4v*)(Vt + (size_t)(n - 3072) * 4096 + m0) = v;
            }
        }
    }
}

// ---------------- RoPE, in-place on QKV [S][4096] (q cols 0..2047, k cols 2048..3071) --
__global__ __launch_bounds__(256) void rope_kernel(short* __restrict__ QKV,
                                                   const int* __restrict__ pos)
{
    int t = blockIdx.x * 256 + threadIdx.x;   // S * 12 * 128 threads
    int d   = t & 127;
    int rem = t >> 7;
    int hh  = rem % 12;                        // 0..7 q-heads, 8..11 k-heads
    int s   = rem / 12;
    float p   = (float)pos[s];
    float inv = __expf(-9.210340371976184f * ((float)d * (1.0f/128.0f)));  // 10000^(-d/128)
    float ang = p * inv;
    float sn, cs;
    sincosf(ang, &sn, &cs);
    short* row = QKV + (size_t)s * 4096 + hh * 256;   // hh*256 works for q and k regions
    float x1 = bits2f(row[d]);
    float x2 = bits2f(row[d + 128]);
    row[d]       = bf16bits(x1 * cs - x2 * sn);
    row[d + 128] = bf16bits(x2 * cs + x1 * sn);
}

// ---------------- flash attention v2: 2 waves x 32 queries, KVBLK=64 -----------------
// Block = 128 threads = 2 waves, covers 64 queries of one head. 512 blocks (2/CU).
// LDS (73.7 KB): lK [64 key][256 d] rows 512B, XOR-swz ^((key&7)<<3) on short idx
//                lV [256 d][64 key] rows 128B, XOR-swz ^((d&7)<<3)
//                lP per-wave [32 q][64 k] rows 128B, XOR-swz ^((q&7)<<3)
// All ds_read_b128 patterns land 2-way bank aliasing (free). global_load_lds staging
// uses inverse-swizzled GLOBAL source + linear LDS dest (involution, rule 21).
// Fixed-max softmax p = exp(sv-12); interior tiles skip masking entirely.
__global__ __launch_bounds__(128) void attn_kernel(const short* __restrict__ QKV,
                                                   const short* __restrict__ Vt,
                                                   short* __restrict__ Ob)
{
    __shared__ __align__(16) short lK[64 * 256];      // 32 KB
    __shared__ __align__(16) short lV[256 * 64];      // 32 KB
    __shared__ __align__(16) short lP[2][32 * 64];    // 8 KB (per-wave halves)
    int tid  = threadIdx.x;
    int lane = tid & 63;
    int wave = tid >> 6;                // 0,1
    int col  = lane & 15;
    int quad = lane >> 4;
    int bid  = blockIdx.x;              // g*128 + chunk*2 + hsub (KV-sharing blocks adjacent)
    int g     = bid >> 7;
    int chunk = (bid >> 1) & 63;
    int h     = g * 2 + (bid & 1);
    int qb = chunk * 64;
    int q0 = qb + wave * 32;            // this wave's 32 queries

    // ---- preload Q fragments: qf[mt][c], A-operand (m=col, k=c*32+quad*8+j) ----
    short8 qf[2][8];
    #pragma unroll
    for (int mt = 0; mt < 2; ++mt) {
        const short* Qrow = QKV + (size_t)(q0 + mt*16 + col) * 4096 + h * 256;
        #pragma unroll
        for (int c = 0; c < 8; ++c)
            qf[mt][c] = *(const short8*)(Qrow + c*32 + quad*8);
    }

    // ---- staging descriptors (pre-swizzled global sources) ----
    // K: wave stages keys [wave*32, wave*32+32), 16 instrs, 2 keys (2x512B) each.
    int keyL = wave * 32 + (lane >> 5);       // + 2*i
    int segK = lane & 31;                     // 16B segment within 512B row
    const short* pK[4];
    #pragma unroll
    for (int j = 0; j < 4; ++j) {
        int key = keyL + 2 * j;
        pK[j] = QKV + (size_t)key * 4096 + 2048 + g * 256 + ((segK ^ (key & 7)) << 3);
    }
    short* dK = lK + wave * 32 * 256;         // + 2*i*256 (linear dest)

    // V: wave stages d-rows [wave*128, wave*128+128), 16 instrs, 8 rows (8x128B) each.
    int dL   = wave * 128 + (lane >> 3);      // + 8*i
    int segV = lane & 7;                      // 16B segment within 128B row
    const short* pV = Vt + (size_t)(g * 256 + dL) * 4096 + ((segV ^ (dL & 7)) << 3);
    short* dV = lV + wave * 128 * 64;         // + 8*i*64

    floatx4 o[2][16] = {};
    float psum[2][4] = {};

    int kb_start = qb - (SWIN - 1);
    if (kb_start < 0) kb_start = 0;
    kb_start &= ~63;

    for (int kb = kb_start; kb < qb + 64; kb += 64) {
        __syncthreads();                                   // prev-iter readers done
        #pragma unroll
        for (int i = 0; i < 16; ++i)
            gload_lds16(pK[i & 3] + (size_t)(kb + 8 * (i >> 2)) * 4096, dK + 2*i*256);
        #pragma unroll
        for (int i = 0; i < 16; ++i)
            gload_lds16(pV + (size_t)(8 * i) * 4096 + kb, dV + 8*i*64);
        __syncthreads();                                   // staging drained

        // ---- QK^T: sc[mt][kt] over 8 k-chunks ----
        floatx4 sc[2][4] = {};
        #pragma unroll
        for (int c = 0; c < 8; ++c) {
            short8 kf[4];
            #pragma unroll
            for (int kt = 0; kt < 4; ++kt)
                kf[kt] = *(const short8*)(lK + (kt*16 + col) * 256
                                             + ((c*32 + quad*8) ^ ((col & 7) << 3)));
            #pragma unroll
            for (int mt = 0; mt < 2; ++mt)
                #pragma unroll
                for (int kt = 0; kt < 4; ++kt)
                    sc[mt][kt] = __builtin_amdgcn_mfma_f32_16x16x32_bf16(qf[mt][c], kf[kt], sc[mt][kt], 0, 0, 0);
        }

        // ---- scale, softcap (poly tanh), mask (edges only), exp(sv-12), P->LDS ----
        bool full = (kb + 64 <= q0) && (kb + SWIN >= q0 + 32);   // wave-uniform
#define SOFTMAX_BODY(MASKED)                                                        \
        _Pragma("unroll")                                                           \
        for (int mt = 0; mt < 2; ++mt)                                              \
            _Pragma("unroll")                                                       \
            for (int kt = 0; kt < 4; ++kt)                                          \
                _Pragma("unroll")                                                   \
                for (int r = 0; r < 4; ++r) {                                       \
                    float y  = sc[mt][kt][r] * 0.0625f;                             \
                    float x2 = y * y * 4.0e-4f;                                     \
                    float sv = y * (1.0f + x2 * (-0.33333333f + x2 * 0.13333333f)); \
                    float p  = __expf(sv - 12.0f);                                  \
                    if (MASKED) {                                                   \
                        int i = q0 + mt*16 + quad*4 + r;                            \
                        int j = kb + kt*16 + col;                                   \
                        bool v = (j <= i) && ((i - j) < SWIN);                      \
                        p = v ? p : 0.0f;                                           \
                    }                                                               \
                    psum[mt][r] += p;                                               \
                    int q = mt*16 + quad*4 + r;                                     \
                    lP[wave][q*64 + ((kt*16 + col) ^ ((q & 7) << 3))] = bf16bits(p);\
                }
        if (full) { SOFTMAX_BODY(false) } else { SOFTMAX_BODY(true) }
#undef SOFTMAX_BODY

        __threadfence_block();   // order P writes -> P reads (C-layout -> A-layout)

        short8 pa[2][2];
        #pragma unroll
        for (int mt = 0; mt < 2; ++mt)
            #pragma unroll
            for (int kh = 0; kh < 2; ++kh)
                pa[mt][kh] = *(const short8*)(&lP[wave][(mt*16 + col) * 64
                                                 + ((kh*32 + quad*8) ^ ((col & 7) << 3))]);

        // ---- PV: o[mt][nt] += P * V over 2 key-halves ----
        #pragma unroll
        for (int nt = 0; nt < 16; ++nt) {
            short8 vf0 = *(const short8*)(lV + (nt*16 + col) * 64
                                             + ((quad*8)      ^ ((col & 7) << 3)));
            short8 vf1 = *(const short8*)(lV + (nt*16 + col) * 64
                                             + ((32 + quad*8) ^ ((col & 7) << 3)));
            #pragma unroll
            for (int mt = 0; mt < 2; ++mt) {
                o[mt][nt] = __builtin_amdgcn_mfma_f32_16x16x32_bf16(pa[mt][0], vf0, o[mt][nt], 0, 0, 0);
                o[mt][nt] = __builtin_amdgcn_mfma_f32_16x16x32_bf16(pa[mt][1], vf1, o[mt][nt], 0, 0, 0);
            }
        }
    }

    // ---- epilogue: reduce psum over 16 col-lanes, store Ob = o/psum ----
    #pragma unroll
    for (int off = 1; off < 16; off <<= 1)
        #pragma unroll
        for (int mt = 0; mt < 2; ++mt)
            #pragma unroll
            for (int r = 0; r < 4; ++r)
                psum[mt][r] += __shfl_xor(psum[mt][r], off, 64);

    #pragma unroll
    for (int mt = 0; mt < 2; ++mt)
        #pragma unroll
        for (int nt = 0; nt < 16; ++nt)
            #pragma unroll
            for (int r = 0; r < 4; ++r) {
                int i = q0 + mt*16 + quad*4 + r;
                Ob[(size_t)i * 2048 + h*256 + nt*16 + col] = bf16bits(o[mt][nt][r] / psum[mt][r]);
            }
}

// ---------------- launcher ----------------
extern "C" void kernel_launch(void* const* d_in, const int* in_sizes, int n_in,
                              void* d_out, int out_size, void* d_ws, size_t ws_size,
                              hipStream_t stream)
{
    const float* X  = (const float*)d_in[0];
    const int*  pos = (const int*)d_in[1];
    const float* Wq = (const float*)d_in[2];
    const float* Wk = (const float*)d_in[3];
    const float* Wv = (const float*)d_in[4];
    const float* Wo = (const float*)d_in[5];
    float* out = (float*)d_out;
    char* ws = (char*)d_ws;

    // workspace layout (bytes); Ob overlaps Xb (dead after gemm_qkv)
    short* Xb    = (short*)(ws + 0);          // 4096x2304 bf16 = 18,874,368
    short* Wqkvb = (short*)(ws + 18874368);   // 4096x2304 bf16 = 18,874,368
    short* Wob   = (short*)(ws + 37748736);   // 2304x2048 bf16 =  9,437,184
    short* QKVb  = (short*)(ws + 47185920);   // 4096x4096 bf16 = 33,554,432
    short* Vt    = (short*)(ws + 80740352);   // 1024x4096 bf16 =  8,388,608  (end 89,128,960)
    short* Ob    = (short*)(ws + 0);          // 4096x2048 bf16 = 16,777,216  (reuses Xb)

    cast_f32_bf16<<<9216, 256, 0, stream>>>(X,  Xb,  2359296);
    cast_wqkv<<<9216, 256, 0, stream>>>(Wq, Wk, Wv, Wqkvb);
    cast_f32_bf16<<<4608, 256, 0, stream>>>(Wo, Wob, 1179648);

    gemm_qkv<<<dim3(32,32), 256, 0, stream>>>(Xb, Wqkvb, QKVb, Vt);

    rope_kernel<<<24576, 256, 0, stream>>>(QKVb, pos);

    attn_kernel<<<512, 128, 0, stream>>>(QKVb, Vt, Ob);

    gemm_lds<2><<<dim3(18,32), 256, 0, stream>>>(Ob, Wob, out, 4096, 2304, 2048, 2304);
}

// Round 2
// 473.510 us; speedup vs baseline: 1.0272x; 1.0272x over previous
//
#include <hip/hip_runtime.h>
#include <hip/hip_bf16.h>

typedef __attribute__((ext_vector_type(8))) short short8;
typedef __attribute__((ext_vector_type(4))) short short4v;
typedef __attribute__((ext_vector_type(4))) float floatx4;
typedef __attribute__((ext_vector_type(8))) _Float16 half8;

#define S_LEN 4096
#define HIDDEN 2304
#define NHEADS 8
#define NKVH 4
#define HDIM 256
#define SWIN 2048

static __device__ __forceinline__ short bf16bits(float x) {
    __hip_bfloat16 h = __float2bfloat16(x);
    return __builtin_bit_cast(short, h);
}
static __device__ __forceinline__ float bits2f(short b) {
    return __bfloat162float(__builtin_bit_cast(__hip_bfloat16, b));
}

static __device__ __forceinline__ void gload_lds16(const short* g, short* l) {
    __builtin_amdgcn_global_load_lds((const __attribute__((address_space(1))) void*)g,
                                     (__attribute__((address_space(3))) void*)l,
                                     16, 0, 0);
}

// ---------------- cast fp32 -> bf16 (4 elems/thread) ----------------
__global__ __launch_bounds__(256) void cast_f32_bf16(const float* __restrict__ in,
                                                     short* __restrict__ out, int n4) {
    int i = blockIdx.x * 256 + threadIdx.x;
    if (i >= n4) return;
    float4 v = ((const float4*)in)[i];
    short4v o;
    o.x = bf16bits(v.x); o.y = bf16bits(v.y); o.z = bf16bits(v.z); o.w = bf16bits(v.w);
    ((short4v*)out)[i] = o;
}

// ---------------- fused W cast: [Wq;Wk;Wv] -> one bf16 [4096][2304] ----------------
__global__ __launch_bounds__(256) void cast_wqkv(const float* __restrict__ Wq,
                                                 const float* __restrict__ Wk,
                                                 const float* __restrict__ Wv,
                                                 short* __restrict__ dst) {
    const int NQ4 = 1179648, NK4 = 589824;      // float4 counts
    int i = blockIdx.x * 256 + threadIdx.x;     // 0 .. 2359295
    const float4* src;
    if (i < NQ4)            src = (const float4*)Wq + i;
    else if (i < NQ4 + NK4) src = (const float4*)Wk + (i - NQ4);
    else                    src = (const float4*)Wv + (i - NQ4 - NK4);
    float4 v = *src;
    short4v o;
    o.x = bf16bits(v.x); o.y = bf16bits(v.y); o.z = bf16bits(v.z); o.w = bf16bits(v.w);
    ((short4v*)dst)[i] = o;
}

// ---------------- generic GEMM (m97-style): C[M,N] = A[M,K]*B[N,K]^T ----------------
template<int MODE>
__global__ __launch_bounds__(256) void gemm_lds(const short* __restrict__ A,
                                                const short* __restrict__ B,
                                                void* __restrict__ Cp,
                                                int M, int N, int K, int ldc)
{
    __shared__ __align__(16) short lA[128 * 32];
    __shared__ __align__(16) short lB[128 * 32];
    int tid  = threadIdx.x;
    int lane = tid & 63;
    int wave = tid >> 6;
    int col  = lane & 15;
    int quad = lane >> 4;
    int m_base = blockIdx.y * 128;
    int n_base = blockIdx.x * 128;
    int wm = (wave >> 1) * 64;
    int wn = (wave & 1) * 64;

    int srow = wave * 32 + (lane >> 2);
    int scol = (lane & 3) * 8;
    const short* gA0 = A + (size_t)(m_base + srow) * K + scol;
    const short* gA1 = gA0 + (size_t)16 * K;
    const short* gB0 = B + (size_t)(n_base + srow) * K + scol;
    const short* gB1 = gB0 + (size_t)16 * K;
    short* lA0 = lA + wave * 1024;
    short* lB0 = lB + wave * 1024;

    floatx4 acc[4][4] = {};

    for (int k0 = 0; k0 < K; k0 += 32) {
        __syncthreads();
        gload_lds16(gA0 + k0, lA0);
        gload_lds16(gA1 + k0, lA0 + 512);
        gload_lds16(gB0 + k0, lB0);
        gload_lds16(gB1 + k0, lB0 + 512);
        __syncthreads();

        short8 af[4], bf[4];
        #pragma unroll
        for (int t = 0; t < 4; ++t) {
            af[t] = *(const short8*)(lA + (wm + t*16 + col) * 32 + quad * 8);
            bf[t] = *(const short8*)(lB + (wn + t*16 + col) * 32 + quad * 8);
        }
        #pragma unroll
        for (int mt = 0; mt < 4; ++mt)
            #pragma unroll
            for (int nt = 0; nt < 4; ++nt)
                acc[mt][nt] = __builtin_amdgcn_mfma_f32_16x16x32_bf16(af[mt], bf[nt], acc[mt][nt], 0, 0, 0);
    }

    #pragma unroll
    for (int mt = 0; mt < 4; ++mt) {
        #pragma unroll
        for (int nt = 0; nt < 4; ++nt) {
            int n  = n_base + wn + nt*16 + col;
            int m0 = m_base + wm + mt*16 + quad*4;
            if (MODE == 0) {
                short* C = (short*)Cp;
                #pragma unroll
                for (int r = 0; r < 4; ++r)
                    C[(size_t)(m0 + r) * ldc + n] = bf16bits(acc[mt][nt][r]);
            } else {
                float* C = (float*)Cp;
                #pragma unroll
                for (int r = 0; r < 4; ++r)
                    C[(size_t)(m0 + r) * ldc + n] = acc[mt][nt][r];
            }
        }
    }
}

// ---------------- fused QKV GEMM: A=Xb[4096][2304], B=Wqkvb[4096][2304] ----------------
__global__ __launch_bounds__(256) void gemm_qkv(const short* __restrict__ A,
                                                const short* __restrict__ B,
                                                short* __restrict__ QKV,
                                                short* __restrict__ Vt)
{
    __shared__ __align__(16) short lA[128 * 32];
    __shared__ __align__(16) short lB[128 * 32];
    const int K = HIDDEN;
    int tid  = threadIdx.x;
    int lane = tid & 63;
    int wave = tid >> 6;
    int col  = lane & 15;
    int quad = lane >> 4;
    int m_base = blockIdx.y * 128;
    int n_base = blockIdx.x * 128;
    int wm = (wave >> 1) * 64;
    int wn = (wave & 1) * 64;

    int srow = wave * 32 + (lane >> 2);
    int scol = (lane & 3) * 8;
    const short* gA0 = A + (size_t)(m_base + srow) * K + scol;
    const short* gA1 = gA0 + (size_t)16 * K;
    const short* gB0 = B + (size_t)(n_base + srow) * K + scol;
    const short* gB1 = gB0 + (size_t)16 * K;
    short* lA0 = lA + wave * 1024;
    short* lB0 = lB + wave * 1024;

    floatx4 acc[4][4] = {};

    for (int k0 = 0; k0 < K; k0 += 32) {
        __syncthreads();
        gload_lds16(gA0 + k0, lA0);
        gload_lds16(gA1 + k0, lA0 + 512);
        gload_lds16(gB0 + k0, lB0);
        gload_lds16(gB1 + k0, lB0 + 512);
        __syncthreads();

        short8 af[4], bf[4];
        #pragma unroll
        for (int t = 0; t < 4; ++t) {
            af[t] = *(const short8*)(lA + (wm + t*16 + col) * 32 + quad * 8);
            bf[t] = *(const short8*)(lB + (wn + t*16 + col) * 32 + quad * 8);
        }
        #pragma unroll
        for (int mt = 0; mt < 4; ++mt)
            #pragma unroll
            for (int nt = 0; nt < 4; ++nt)
                acc[mt][nt] = __builtin_amdgcn_mfma_f32_16x16x32_bf16(af[mt], bf[nt], acc[mt][nt], 0, 0, 0);
    }

    #pragma unroll
    for (int mt = 0; mt < 4; ++mt) {
        #pragma unroll
        for (int nt = 0; nt < 4; ++nt) {
            int n  = n_base + wn + nt*16 + col;
            int m0 = m_base + wm + mt*16 + quad*4;
            if (n_base + wn + nt*16 < 3072) {
                #pragma unroll
                for (int r = 0; r < 4; ++r)
                    QKV[(size_t)(m0 + r) * 4096 + n] = bf16bits(acc[mt][nt][r]);
            } else {
                short4v v;
                v.x = bf16bits(acc[mt][nt][0]);
                v.y = bf16bits(acc[mt][nt][1]);
                v.z = bf16bits(acc[mt][nt][2]);
                v.w = bf16bits(acc[mt][nt][3]);
                *(short4v*)(Vt + (size_t)(n - 3072) * 4096 + m0) = v;
            }
        }
    }
}

// ---------------- RoPE, in-place on QKV [S][4096] ----------------
__global__ __launch_bounds__(256) void rope_kernel(short* __restrict__ QKV,
                                                   const int* __restrict__ pos)
{
    int t = blockIdx.x * 256 + threadIdx.x;   // S * 12 * 128 threads
    int d   = t & 127;
    int rem = t >> 7;
    int hh  = rem % 12;                        // 0..7 q-heads, 8..11 k-heads
    int s   = rem / 12;
    float p   = (float)pos[s];
    float inv = __expf(-9.210340371976184f * ((float)d * (1.0f/128.0f)));  // 10000^(-d/128)
    float ang = p * inv;
    float sn, cs;
    sincosf(ang, &sn, &cs);
    short* row = QKV + (size_t)s * 4096 + hh * 256;
    float x1 = bits2f(row[d]);
    float x2 = bits2f(row[d + 128]);
    row[d]       = bf16bits(x1 * cs - x2 * sn);
    row[d + 128] = bf16bits(x2 * cs + x1 * sn);
}

// ---------------- flash attention v3: dual-head 4-wave blocks + KV-split x2 ----------
// Block = 256 threads = 4 waves. Wave w -> head g*2 + (w>>1), queries qb + (w&1)*32.
// K/V tiles (KVBLK=64) shared by all 4 waves (both heads share KV). Each (g,chunk)
// is split into 2 blocks over the KV-tile range (halves additive: fixed-max softmax).
// Grid 512 blocks, LDS 80KB -> 2 blocks/CU -> 8 waves/CU = 2/SIMD.
// LDS layouts identical to measured-clean v2 forms:
//   lK [64 key][256 d] rows 512B, swz ^((key&7)<<3); lV [256 d][64 k] rows 128B,
//   swz ^((d&7)<<3); lP per-wave [32 q][64 k] rows 128B, swz ^((q&7)<<3).
// Partial O in fp16, partial psum in fp32; combined by combine_kernel.
__global__ __launch_bounds__(256) void attn_kernel(const short* __restrict__ QKV,
                                                   const short* __restrict__ Vt,
                                                   _Float16* __restrict__ Opart,
                                                   float* __restrict__ Psp)
{
    __shared__ __align__(16) short lK[64 * 256];      // 32 KB
    __shared__ __align__(16) short lV[256 * 64];      // 32 KB
    __shared__ __align__(16) short lP[4][32 * 64];    // 16 KB
    int tid  = threadIdx.x;
    int lane = tid & 63;
    int wave = tid >> 6;                // 0..3
    int col  = lane & 15;
    int quad = lane >> 4;
    int bid  = blockIdx.x;              // g*128 + chunk*2 + half
    int g     = bid >> 7;
    int chunk = (bid >> 1) & 63;
    int half  = bid & 1;
    int h     = g * 2 + (wave >> 1);
    int qb = chunk * 64;
    int q0 = qb + (wave & 1) * 32;      // this wave's 32 queries

    // ---- preload Q fragments: qf[mt][c], A-operand (m=col, k=c*32+quad*8+j) ----
    short8 qf[2][8];
    #pragma unroll
    for (int mt = 0; mt < 2; ++mt) {
        const short* Qrow = QKV + (size_t)(q0 + mt*16 + col) * 4096 + h * 256;
        #pragma unroll
        for (int c = 0; c < 8; ++c)
            qf[mt][c] = *(const short8*)(Qrow + c*32 + quad*8);
    }

    // ---- staging descriptors (pre-swizzled global sources, per-wave quarters) ----
    // K: wave stages keys [wave*16, wave*16+16), 8 instrs, 2 keys (2x512B) each.
    int keyL = wave * 16 + (lane >> 5);       // + 2*(i&3) + 8*(i>>2)
    int segK = lane & 31;                     // 16B segment within 512B row
    const short* pK[4];
    #pragma unroll
    for (int j = 0; j < 4; ++j) {
        int key = keyL + 2 * j;
        pK[j] = QKV + (size_t)key * 4096 + 2048 + g * 256 + ((segK ^ (key & 7)) << 3);
    }
    short* dK = lK + wave * 16 * 256;         // linear dest

    // V: wave stages d-rows [wave*64, wave*64+64), 8 instrs, 8 rows (8x128B) each.
    int dL   = wave * 64 + (lane >> 3);       // + 8*i
    int segV = lane & 7;                      // 16B segment within 128B row
    const short* pV = Vt + (size_t)(g * 256 + dL) * 4096 + ((segV ^ (dL & 7)) << 3);
    short* dV = lV + wave * 64 * 64;

    floatx4 o[2][16] = {};
    float psum[2][4] = {};

    // ---- KV tile range, split in half across the 2 half-blocks ----
    int kb_lo = qb - (SWIN - 1);
    if (kb_lo < 0) kb_lo = 0;
    kb_lo &= ~63;
    int T  = ((qb + 64) - kb_lo) >> 6;
    int T0 = T >> 1;
    int kb_beg = kb_lo + (half ? T0 * 64 : 0);
    int kb_end = kb_lo + (half ? T * 64 : T0 * 64);

    for (int kb = kb_beg; kb < kb_end; kb += 64) {
        __syncthreads();                                   // prev-iter readers done
        #pragma unroll
        for (int i = 0; i < 8; ++i)
            gload_lds16(pK[i & 3] + (size_t)(kb + 8 * (i >> 2)) * 4096, dK + 2*i*256);
        #pragma unroll
        for (int i = 0; i < 8; ++i)
            gload_lds16(pV + (size_t)(8 * i) * 4096 + kb, dV + 8*i*64);
        __syncthreads();                                   // staging drained

        // ---- QK^T: sc[mt][kt] over 8 k-chunks ----
        floatx4 sc[2][4] = {};
        #pragma unroll
        for (int c = 0; c < 8; ++c) {
            short8 kf[4];
            #pragma unroll
            for (int kt = 0; kt < 4; ++kt)
                kf[kt] = *(const short8*)(lK + (kt*16 + col) * 256
                                             + ((c*32 + quad*8) ^ ((col & 7) << 3)));
            #pragma unroll
            for (int mt = 0; mt < 2; ++mt)
                #pragma unroll
                for (int kt = 0; kt < 4; ++kt)
                    sc[mt][kt] = __builtin_amdgcn_mfma_f32_16x16x32_bf16(qf[mt][c], kf[kt], sc[mt][kt], 0, 0, 0);
        }

        // ---- scale, softcap (poly tanh), mask (edges only), exp(sv-12), P->LDS ----
        bool full = (kb + 64 <= q0) && (kb + SWIN >= q0 + 32);   // wave-uniform
#define SOFTMAX_BODY(MASKED)                                                        \
        _Pragma("unroll")                                                           \
        for (int mt = 0; mt < 2; ++mt)                                              \
            _Pragma("unroll")                                                       \
            for (int kt = 0; kt < 4; ++kt)                                          \
                _Pragma("unroll")                                                   \
                for (int r = 0; r < 4; ++r) {                                       \
                    float y  = sc[mt][kt][r] * 0.0625f;                             \
                    float x2 = y * y * 4.0e-4f;                                     \
                    float sv = y * (1.0f + x2 * (-0.33333333f + x2 * 0.13333333f)); \
                    float p  = __expf(sv - 12.0f);                                  \
                    if (MASKED) {                                                   \
                        int i = q0 + mt*16 + quad*4 + r;                            \
                        int j = kb + kt*16 + col;                                   \
                        bool v = (j <= i) && ((i - j) < SWIN);                      \
                        p = v ? p : 0.0f;                                           \
                    }                                                               \
                    psum[mt][r] += p;                                               \
                    int q = mt*16 + quad*4 + r;                                     \
                    lP[wave][q*64 + ((kt*16 + col) ^ ((q & 7) << 3))] = bf16bits(p);\
                }
        if (full) { SOFTMAX_BODY(false) } else { SOFTMAX_BODY(true) }
#undef SOFTMAX_BODY

        __threadfence_block();   // order P writes -> P reads (C-layout -> A-layout)

        short8 pa[2][2];
        #pragma unroll
        for (int mt = 0; mt < 2; ++mt)
            #pragma unroll
            for (int kh = 0; kh < 2; ++kh)
                pa[mt][kh] = *(const short8*)(&lP[wave][(mt*16 + col) * 64
                                                 + ((kh*32 + quad*8) ^ ((col & 7) << 3))]);

        // ---- PV: o[mt][nt] += P * V over 2 key-halves ----
        #pragma unroll
        for (int nt = 0; nt < 16; ++nt) {
            short8 vf0 = *(const short8*)(lV + (nt*16 + col) * 64
                                             + ((quad*8)      ^ ((col & 7) << 3)));
            short8 vf1 = *(const short8*)(lV + (nt*16 + col) * 64
                                             + ((32 + quad*8) ^ ((col & 7) << 3)));
            #pragma unroll
            for (int mt = 0; mt < 2; ++mt) {
                o[mt][nt] = __builtin_amdgcn_mfma_f32_16x16x32_bf16(pa[mt][0], vf0, o[mt][nt], 0, 0, 0);
                o[mt][nt] = __builtin_amdgcn_mfma_f32_16x16x32_bf16(pa[mt][1], vf1, o[mt][nt], 0, 0, 0);
            }
        }
    }

    // ---- epilogue: reduce psum over 16 col-lanes; store fp16 o-partial + psum ----
    #pragma unroll
    for (int off = 1; off < 16; off <<= 1)
        #pragma unroll
        for (int mt = 0; mt < 2; ++mt)
            #pragma unroll
            for (int r = 0; r < 4; ++r)
                psum[mt][r] += __shfl_xor(psum[mt][r], off, 64);

    _Float16* Op = Opart + (size_t)half * (4096 * 2048);
    #pragma unroll
    for (int mt = 0; mt < 2; ++mt)
        #pragma unroll
        for (int nt = 0; nt < 16; ++nt)
            #pragma unroll
            for (int r = 0; r < 4; ++r) {
                int i = q0 + mt*16 + quad*4 + r;
                Op[(size_t)i * 2048 + h*256 + nt*16 + col] = (_Float16)o[mt][nt][r];
            }
    if (col == 0) {
        #pragma unroll
        for (int mt = 0; mt < 2; ++mt)
            #pragma unroll
            for (int r = 0; r < 4; ++r)
                Psp[half * 32768 + h * 4096 + q0 + mt*16 + quad*4 + r] = psum[mt][r];
    }
}

// ---------------- combine halves: Ob = (O0 + O1) / (ps0 + ps1), bf16, in-place over O0
__global__ __launch_bounds__(256) void combine_kernel(const _Float16* __restrict__ O0,
                                                      const _Float16* __restrict__ O1,
                                                      const float* __restrict__ Ps,
                                                      short* __restrict__ Ob)
{
    int t = blockIdx.x * 256 + threadIdx.x;      // 1,048,576 threads x 8 elems
    size_t base = (size_t)t * 8;
    int q = (int)(base >> 11);
    int h = (int)((base >> 8) & 7);
    float inv = 1.0f / (Ps[h * 4096 + q] + Ps[32768 + h * 4096 + q]);
    half8 a = *(const half8*)(O0 + base);
    half8 b = *(const half8*)(O1 + base);
    short8 o;
    #pragma unroll
    for (int j = 0; j < 8; ++j)
        o[j] = bf16bits(((float)a[j] + (float)b[j]) * inv);
    *(short8*)(Ob + base) = o;
}

// ---------------- launcher ----------------
extern "C" void kernel_launch(void* const* d_in, const int* in_sizes, int n_in,
                              void* d_out, int out_size, void* d_ws, size_t ws_size,
                              hipStream_t stream)
{
    const float* X  = (const float*)d_in[0];
    const int*  pos = (const int*)d_in[1];
    const float* Wq = (const float*)d_in[2];
    const float* Wk = (const float*)d_in[3];
    const float* Wv = (const float*)d_in[4];
    const float* Wo = (const float*)d_in[5];
    float* out = (float*)d_out;
    char* ws = (char*)d_ws;

    // workspace layout (bytes):
    //   [0, 18.9M)   Xb          (dead after gemm_qkv -> reused for Opart half0)
    //   [18.9M,37.7M) Wqkvb      (dead after gemm_qkv -> reused for Opart half1 + Psp)
    //   Opart: fp16 [2][4096][2048] = 33,554,432 B at offset 0
    //   Psp:   fp32 [2][8][4096]    =    262,144 B at offset 33,554,432
    //   Ob: bf16 [4096][2048] written in-place over Opart half0 (offset 0)
    short* Xb    = (short*)(ws + 0);          // 4096x2304 bf16 = 18,874,368
    short* Wqkvb = (short*)(ws + 18874368);   // 4096x2304 bf16 = 18,874,368
    short* Wob   = (short*)(ws + 37748736);   // 2304x2048 bf16 =  9,437,184
    short* QKVb  = (short*)(ws + 47185920);   // 4096x4096 bf16 = 33,554,432
    short* Vt    = (short*)(ws + 80740352);   // 1024x4096 bf16 =  8,388,608  (end 89,128,960)
    _Float16* Opart = (_Float16*)(ws + 0);    // 2 x 16 MB fp16 partials
    float*    Psp   = (float*)(ws + 33554432);
    short*    Ob    = (short*)(ws + 0);

    cast_f32_bf16<<<9216, 256, 0, stream>>>(X,  Xb,  2359296);
    cast_wqkv<<<9216, 256, 0, stream>>>(Wq, Wk, Wv, Wqkvb);
    cast_f32_bf16<<<4608, 256, 0, stream>>>(Wo, Wob, 1179648);

    gemm_qkv<<<dim3(32,32), 256, 0, stream>>>(Xb, Wqkvb, QKVb, Vt);

    rope_kernel<<<24576, 256, 0, stream>>>(QKVb, pos);

    attn_kernel<<<512, 256, 0, stream>>>(QKVb, Vt, Opart, Psp);

    combine_kernel<<<4096, 256, 0, stream>>>(Opart, Opart + (size_t)4096*2048, Psp, Ob);

    gemm_lds<2><<<dim3(18,32), 256, 0, stream>>>(Ob, Wob, out, 4096, 2304, 2048, 2304);
}

// Round 3
// 472.523 us; speedup vs baseline: 1.0293x; 1.0021x over previous
//
#include <hip/hip_runtime.h>
#include <hip/hip_bf16.h>

typedef __attribute__((ext_vector_type(8))) short short8;
typedef __attribute__((ext_vector_type(4))) short short4v;
typedef __attribute__((ext_vector_type(4))) float floatx4;
typedef __attribute__((ext_vector_type(8))) _Float16 half8;

#define S_LEN 4096
#define HIDDEN 2304
#define NHEADS 8
#define NKVH 4
#define HDIM 256
#define SWIN 2048

static __device__ __forceinline__ short bf16bits(float x) {
    __hip_bfloat16 h = __float2bfloat16(x);
    return __builtin_bit_cast(short, h);
}
static __device__ __forceinline__ float bits2f(short b) {
    return __bfloat162float(__builtin_bit_cast(__hip_bfloat16, b));
}

static __device__ __forceinline__ void gload_lds16(const short* g, short* l) {
    __builtin_amdgcn_global_load_lds((const __attribute__((address_space(1))) void*)g,
                                     (__attribute__((address_space(3))) void*)l,
                                     16, 0, 0);
}

// ---------------- cast fp32 -> bf16 (4 elems/thread) ----------------
__global__ __launch_bounds__(256) void cast_f32_bf16(const float* __restrict__ in,
                                                     short* __restrict__ out, int n4) {
    int i = blockIdx.x * 256 + threadIdx.x;
    if (i >= n4) return;
    float4 v = ((const float4*)in)[i];
    short4v o;
    o.x = bf16bits(v.x); o.y = bf16bits(v.y); o.z = bf16bits(v.z); o.w = bf16bits(v.w);
    ((short4v*)out)[i] = o;
}

// ---------------- fused W cast: [Wq;Wk;Wv] -> one bf16 [4096][2304] ----------------
__global__ __launch_bounds__(256) void cast_wqkv(const float* __restrict__ Wq,
                                                 const float* __restrict__ Wk,
                                                 const float* __restrict__ Wv,
                                                 short* __restrict__ dst) {
    const int NQ4 = 1179648, NK4 = 589824;      // float4 counts
    int i = blockIdx.x * 256 + threadIdx.x;     // 0 .. 2359295
    const float4* src;
    if (i < NQ4)            src = (const float4*)Wq + i;
    else if (i < NQ4 + NK4) src = (const float4*)Wk + (i - NQ4);
    else                    src = (const float4*)Wv + (i - NQ4 - NK4);
    float4 v = *src;
    short4v o;
    o.x = bf16bits(v.x); o.y = bf16bits(v.y); o.z = bf16bits(v.z); o.w = bf16bits(v.w);
    ((short4v*)dst)[i] = o;
}

// ---------------- generic GEMM (m97-style): C[M,N] = A[M,K]*B[N,K]^T ----------------
template<int MODE>
__global__ __launch_bounds__(256) void gemm_lds(const short* __restrict__ A,
                                                const short* __restrict__ B,
                                                void* __restrict__ Cp,
                                                int M, int N, int K, int ldc)
{
    __shared__ __align__(16) short lA[128 * 32];
    __shared__ __align__(16) short lB[128 * 32];
    int tid  = threadIdx.x;
    int lane = tid & 63;
    int wave = tid >> 6;
    int col  = lane & 15;
    int quad = lane >> 4;
    int m_base = blockIdx.y * 128;
    int n_base = blockIdx.x * 128;
    int wm = (wave >> 1) * 64;
    int wn = (wave & 1) * 64;

    int srow = wave * 32 + (lane >> 2);
    int scol = (lane & 3) * 8;
    const short* gA0 = A + (size_t)(m_base + srow) * K + scol;
    const short* gA1 = gA0 + (size_t)16 * K;
    const short* gB0 = B + (size_t)(n_base + srow) * K + scol;
    const short* gB1 = gB0 + (size_t)16 * K;
    short* lA0 = lA + wave * 1024;
    short* lB0 = lB + wave * 1024;

    floatx4 acc[4][4] = {};

    for (int k0 = 0; k0 < K; k0 += 32) {
        __syncthreads();
        gload_lds16(gA0 + k0, lA0);
        gload_lds16(gA1 + k0, lA0 + 512);
        gload_lds16(gB0 + k0, lB0);
        gload_lds16(gB1 + k0, lB0 + 512);
        __syncthreads();

        short8 af[4], bf[4];
        #pragma unroll
        for (int t = 0; t < 4; ++t) {
            af[t] = *(const short8*)(lA + (wm + t*16 + col) * 32 + quad * 8);
            bf[t] = *(const short8*)(lB + (wn + t*16 + col) * 32 + quad * 8);
        }
        #pragma unroll
        for (int mt = 0; mt < 4; ++mt)
            #pragma unroll
            for (int nt = 0; nt < 4; ++nt)
                acc[mt][nt] = __builtin_amdgcn_mfma_f32_16x16x32_bf16(af[mt], bf[nt], acc[mt][nt], 0, 0, 0);
    }

    #pragma unroll
    for (int mt = 0; mt < 4; ++mt) {
        #pragma unroll
        for (int nt = 0; nt < 4; ++nt) {
            int n  = n_base + wn + nt*16 + col;
            int m0 = m_base + wm + mt*16 + quad*4;
            if (MODE == 0) {
                short* C = (short*)Cp;
                #pragma unroll
                for (int r = 0; r < 4; ++r)
                    C[(size_t)(m0 + r) * ldc + n] = bf16bits(acc[mt][nt][r]);
            } else {
                float* C = (float*)Cp;
                #pragma unroll
                for (int r = 0; r < 4; ++r)
                    C[(size_t)(m0 + r) * ldc + n] = acc[mt][nt][r];
            }
        }
    }
}

// ---------------- fused QKV GEMM: A=Xb[4096][2304], B=Wqkvb[4096][2304] ----------------
__global__ __launch_bounds__(256) void gemm_qkv(const short* __restrict__ A,
                                                const short* __restrict__ B,
                                                short* __restrict__ QKV,
                                                short* __restrict__ Vt)
{
    __shared__ __align__(16) short lA[128 * 32];
    __shared__ __align__(16) short lB[128 * 32];
    const int K = HIDDEN;
    int tid  = threadIdx.x;
    int lane = tid & 63;
    int wave = tid >> 6;
    int col  = lane & 15;
    int quad = lane >> 4;
    int m_base = blockIdx.y * 128;
    int n_base = blockIdx.x * 128;
    int wm = (wave >> 1) * 64;
    int wn = (wave & 1) * 64;

    int srow = wave * 32 + (lane >> 2);
    int scol = (lane & 3) * 8;
    const short* gA0 = A + (size_t)(m_base + srow) * K + scol;
    const short* gA1 = gA0 + (size_t)16 * K;
    const short* gB0 = B + (size_t)(n_base + srow) * K + scol;
    const short* gB1 = gB0 + (size_t)16 * K;
    short* lA0 = lA + wave * 1024;
    short* lB0 = lB + wave * 1024;

    floatx4 acc[4][4] = {};

    for (int k0 = 0; k0 < K; k0 += 32) {
        __syncthreads();
        gload_lds16(gA0 + k0, lA0);
        gload_lds16(gA1 + k0, lA0 + 512);
        gload_lds16(gB0 + k0, lB0);
        gload_lds16(gB1 + k0, lB0 + 512);
        __syncthreads();

        short8 af[4], bf[4];
        #pragma unroll
        for (int t = 0; t < 4; ++t) {
            af[t] = *(const short8*)(lA + (wm + t*16 + col) * 32 + quad * 8);
            bf[t] = *(const short8*)(lB + (wn + t*16 + col) * 32 + quad * 8);
        }
        #pragma unroll
        for (int mt = 0; mt < 4; ++mt)
            #pragma unroll
            for (int nt = 0; nt < 4; ++nt)
                acc[mt][nt] = __builtin_amdgcn_mfma_f32_16x16x32_bf16(af[mt], bf[nt], acc[mt][nt], 0, 0, 0);
    }

    #pragma unroll
    for (int mt = 0; mt < 4; ++mt) {
        #pragma unroll
        for (int nt = 0; nt < 4; ++nt) {
            int n  = n_base + wn + nt*16 + col;
            int m0 = m_base + wm + mt*16 + quad*4;
            if (n_base + wn + nt*16 < 3072) {
                #pragma unroll
                for (int r = 0; r < 4; ++r)
                    QKV[(size_t)(m0 + r) * 4096 + n] = bf16bits(acc[mt][nt][r]);
            } else {
                short4v v;
                v.x = bf16bits(acc[mt][nt][0]);
                v.y = bf16bits(acc[mt][nt][1]);
                v.z = bf16bits(acc[mt][nt][2]);
                v.w = bf16bits(acc[mt][nt][3]);
                *(short4v*)(Vt + (size_t)(n - 3072) * 4096 + m0) = v;
            }
        }
    }
}

// ---------------- RoPE, in-place on QKV [S][4096] ----------------
__global__ __launch_bounds__(256) void rope_kernel(short* __restrict__ QKV,
                                                   const int* __restrict__ pos)
{
    int t = blockIdx.x * 256 + threadIdx.x;   // S * 12 * 128 threads
    int d   = t & 127;
    int rem = t >> 7;
    int hh  = rem % 12;                        // 0..7 q-heads, 8..11 k-heads
    int s   = rem / 12;
    float p   = (float)pos[s];
    float inv = __expf(-9.210340371976184f * ((float)d * (1.0f/128.0f)));  // 10000^(-d/128)
    float ang = p * inv;
    float sn, cs;
    sincosf(ang, &sn, &cs);
    short* row = QKV + (size_t)s * 4096 + hh * 256;
    float x1 = bits2f(row[d]);
    float x2 = bits2f(row[d + 128]);
    row[d]       = bf16bits(x1 * cs - x2 * sn);
    row[d + 128] = bf16bits(x2 * cs + x1 * sn);
}

// ---------------- flash attention v4: dual-head 4-wave blocks, KV-split x2, 64KB LDS --
// Block = 256 threads = 4 waves. Wave w -> head g*2 + (w>>1), queries qb + (w&1)*32.
// LDS cut 80->64 KB by overlaying lP onto lK (lK dead after QK^T within an iter;
// one extra __syncthreads orders QK^T reads before P writes). 2 blocks/CU resident
// (128 KB LDS, VGPR<=256) -> 8 waves/CU: one block's staging stalls overlap the
// other's MFMA. s_setprio(1) wraps MFMA clusters (T5, independent-block regime).
// Layouts (measured conflict-clean):
//   lK [64 key][256 d] rows 512B, swz ^((key&7)<<3); lV [256 d][64 k] rows 128B,
//   swz ^((d&7)<<3); lP per-wave [32 q][64 k] rows 128B, swz ^((q&7)<<3).
__global__ __launch_bounds__(256) void attn_kernel(const short* __restrict__ QKV,
                                                   const short* __restrict__ Vt,
                                                   _Float16* __restrict__ Opart,
                                                   float* __restrict__ Psp)
{
    __shared__ __align__(16) short lK[64 * 256];      // 32 KB (first 16 KB reused as lP)
    __shared__ __align__(16) short lV[256 * 64];      // 32 KB
    int tid  = threadIdx.x;
    int lane = tid & 63;
    int wave = tid >> 6;                // 0..3
    int col  = lane & 15;
    int quad = lane >> 4;
    int bid  = blockIdx.x;              // g*128 + chunk*2 + half
    int g     = bid >> 7;
    int chunk = (bid >> 1) & 63;
    int half  = bid & 1;
    int h     = g * 2 + (wave >> 1);
    int qb = chunk * 64;
    int q0 = qb + (wave & 1) * 32;      // this wave's 32 queries

    short* lPw = lK + wave * 2048;      // per-wave [32 q][64 k] overlay on lK

    // ---- preload Q fragments: qf[mt][c], A-operand (m=col, k=c*32+quad*8+j) ----
    short8 qf[2][8];
    #pragma unroll
    for (int mt = 0; mt < 2; ++mt) {
        const short* Qrow = QKV + (size_t)(q0 + mt*16 + col) * 4096 + h * 256;
        #pragma unroll
        for (int c = 0; c < 8; ++c)
            qf[mt][c] = *(const short8*)(Qrow + c*32 + quad*8);
    }

    // ---- staging descriptors (pre-swizzled global sources, per-wave quarters) ----
    // K: wave stages keys [wave*16, wave*16+16), 8 instrs, 2 keys (2x512B) each.
    int keyL = wave * 16 + (lane >> 5);       // + 2*(i&3) + 8*(i>>2)
    int segK = lane & 31;                     // 16B segment within 512B row
    const short* pK[4];
    #pragma unroll
    for (int j = 0; j < 4; ++j) {
        int key = keyL + 2 * j;
        pK[j] = QKV + (size_t)key * 4096 + 2048 + g * 256 + ((segK ^ (key & 7)) << 3);
    }
    short* dK = lK + wave * 16 * 256;         // linear dest

    // V: wave stages d-rows [wave*64, wave*64+64), 8 instrs, 8 rows (8x128B) each.
    int dL   = wave * 64 + (lane >> 3);       // + 8*i
    int segV = lane & 7;                      // 16B segment within 128B row
    const short* pV = Vt + (size_t)(g * 256 + dL) * 4096 + ((segV ^ (dL & 7)) << 3);
    short* dV = lV + wave * 64 * 64;

    floatx4 o[2][16] = {};
    float psum[2][4] = {};

    // ---- KV tile range, split in half across the 2 half-blocks ----
    int kb_lo = qb - (SWIN - 1);
    if (kb_lo < 0) kb_lo = 0;
    kb_lo &= ~63;
    int T  = ((qb + 64) - kb_lo) >> 6;
    int T0 = T >> 1;
    int kb_beg = kb_lo + (half ? T0 * 64 : 0);
    int kb_end = kb_lo + (half ? T * 64 : T0 * 64);

    for (int kb = kb_beg; kb < kb_end; kb += 64) {
        __syncthreads();                                   // prev-iter readers done
        #pragma unroll
        for (int i = 0; i < 8; ++i)
            gload_lds16(pK[i & 3] + (size_t)(kb + 8 * (i >> 2)) * 4096, dK + 2*i*256);
        #pragma unroll
        for (int i = 0; i < 8; ++i)
            gload_lds16(pV + (size_t)(8 * i) * 4096 + kb, dV + 8*i*64);
        __syncthreads();                                   // staging drained

        // ---- QK^T: sc[mt][kt] over 8 k-chunks ----
        floatx4 sc[2][4] = {};
        __builtin_amdgcn_s_setprio(1);
        #pragma unroll
        for (int c = 0; c < 8; ++c) {
            short8 kf[4];
            #pragma unroll
            for (int kt = 0; kt < 4; ++kt)
                kf[kt] = *(const short8*)(lK + (kt*16 + col) * 256
                                             + ((c*32 + quad*8) ^ ((col & 7) << 3)));
            #pragma unroll
            for (int mt = 0; mt < 2; ++mt)
                #pragma unroll
                for (int kt = 0; kt < 4; ++kt)
                    sc[mt][kt] = __builtin_amdgcn_mfma_f32_16x16x32_bf16(qf[mt][c], kf[kt], sc[mt][kt], 0, 0, 0);
        }
        __builtin_amdgcn_s_setprio(0);

        __syncthreads();   // all waves done reading lK before lP overlay writes

        // ---- scale, softcap (poly tanh), mask (edges only), exp(sv-12), P->LDS ----
        bool full = (kb + 64 <= q0) && (kb + SWIN >= q0 + 32);   // wave-uniform
#define SOFTMAX_BODY(MASKED)                                                        \
        _Pragma("unroll")                                                           \
        for (int mt = 0; mt < 2; ++mt)                                              \
            _Pragma("unroll")                                                       \
            for (int kt = 0; kt < 4; ++kt)                                          \
                _Pragma("unroll")                                                   \
                for (int r = 0; r < 4; ++r) {                                       \
                    float y  = sc[mt][kt][r] * 0.0625f;                             \
                    float x2 = y * y * 4.0e-4f;                                     \
                    float sv = y * (1.0f + x2 * (-0.33333333f + x2 * 0.13333333f)); \
                    float p  = __expf(sv - 12.0f);                                  \
                    if (MASKED) {                                                   \
                        int i = q0 + mt*16 + quad*4 + r;                            \
                        int j = kb + kt*16 + col;                                   \
                        bool v = (j <= i) && ((i - j) < SWIN);                      \
                        p = v ? p : 0.0f;                                           \
                    }                                                               \
                    psum[mt][r] += p;                                               \
                    int q = mt*16 + quad*4 + r;                                     \
                    lPw[q*64 + ((kt*16 + col) ^ ((q & 7) << 3))] = bf16bits(p);     \
                }
        if (full) { SOFTMAX_BODY(false) } else { SOFTMAX_BODY(true) }
#undef SOFTMAX_BODY

        __threadfence_block();   // order P writes -> P reads (C-layout -> A-layout)

        short8 pa[2][2];
        #pragma unroll
        for (int mt = 0; mt < 2; ++mt)
            #pragma unroll
            for (int kh = 0; kh < 2; ++kh)
                pa[mt][kh] = *(const short8*)(&lPw[(mt*16 + col) * 64
                                                 + ((kh*32 + quad*8) ^ ((col & 7) << 3))]);

        // ---- PV: o[mt][nt] += P * V over 2 key-halves ----
        __builtin_amdgcn_s_setprio(1);
        #pragma unroll
        for (int nt = 0; nt < 16; ++nt) {
            short8 vf0 = *(const short8*)(lV + (nt*16 + col) * 64
                                             + ((quad*8)      ^ ((col & 7) << 3)));
            short8 vf1 = *(const short8*)(lV + (nt*16 + col) * 64
                                             + ((32 + quad*8) ^ ((col & 7) << 3)));
            #pragma unroll
            for (int mt = 0; mt < 2; ++mt) {
                o[mt][nt] = __builtin_amdgcn_mfma_f32_16x16x32_bf16(pa[mt][0], vf0, o[mt][nt], 0, 0, 0);
                o[mt][nt] = __builtin_amdgcn_mfma_f32_16x16x32_bf16(pa[mt][1], vf1, o[mt][nt], 0, 0, 0);
            }
        }
        __builtin_amdgcn_s_setprio(0);
    }

    // ---- epilogue: reduce psum over 16 col-lanes; store fp16 o-partial + psum ----
    #pragma unroll
    for (int off = 1; off < 16; off <<= 1)
        #pragma unroll
        for (int mt = 0; mt < 2; ++mt)
            #pragma unroll
            for (int r = 0; r < 4; ++r)
                psum[mt][r] += __shfl_xor(psum[mt][r], off, 64);

    _Float16* Op = Opart + (size_t)half * (4096 * 2048);
    #pragma unroll
    for (int mt = 0; mt < 2; ++mt)
        #pragma unroll
        for (int nt = 0; nt < 16; ++nt)
            #pragma unroll
            for (int r = 0; r < 4; ++r) {
                int i = q0 + mt*16 + quad*4 + r;
                Op[(size_t)i * 2048 + h*256 + nt*16 + col] = (_Float16)o[mt][nt][r];
            }
    if (col == 0) {
        #pragma unroll
        for (int mt = 0; mt < 2; ++mt)
            #pragma unroll
            for (int r = 0; r < 4; ++r)
                Psp[half * 32768 + h * 4096 + q0 + mt*16 + quad*4 + r] = psum[mt][r];
    }
}

// ---------------- combine halves: Ob = (O0 + O1) / (ps0 + ps1), bf16, in-place over O0
__global__ __launch_bounds__(256) void combine_kernel(const _Float16* __restrict__ O0,
                                                      const _Float16* __restrict__ O1,
                                                      const float* __restrict__ Ps,
                                                      short* __restrict__ Ob)
{
    int t = blockIdx.x * 256 + threadIdx.x;      // 1,048,576 threads x 8 elems
    size_t base = (size_t)t * 8;
    int q = (int)(base >> 11);
    int h = (int)((base >> 8) & 7);
    float inv = 1.0f / (Ps[h * 4096 + q] + Ps[32768 + h * 4096 + q]);
    half8 a = *(const half8*)(O0 + base);
    half8 b = *(const half8*)(O1 + base);
    short8 o;
    #pragma unroll
    for (int j = 0; j < 8; ++j)
        o[j] = bf16bits(((float)a[j] + (float)b[j]) * inv);
    *(short8*)(Ob + base) = o;
}

// ---------------- launcher ----------------
extern "C" void kernel_launch(void* const* d_in, const int* in_sizes, int n_in,
                              void* d_out, int out_size, void* d_ws, size_t ws_size,
                              hipStream_t stream)
{
    const float* X  = (const float*)d_in[0];
    const int*  pos = (const int*)d_in[1];
    const float* Wq = (const float*)d_in[2];
    const float* Wk = (const float*)d_in[3];
    const float* Wv = (const float*)d_in[4];
    const float* Wo = (const float*)d_in[5];
    float* out = (float*)d_out;
    char* ws = (char*)d_ws;

    // workspace layout (bytes):
    //   Opart: fp16 [2][4096][2048] = 33,554,432 B at offset 0 (over dead Xb/Wqkvb)
    //   Psp:   fp32 [2][8][4096]    =    262,144 B at offset 33,554,432
    //   Ob: bf16 [4096][2048] written in-place over Opart half0 (offset 0)
    short* Xb    = (short*)(ws + 0);          // 4096x2304 bf16 = 18,874,368
    short* Wqkvb = (short*)(ws + 18874368);   // 4096x2304 bf16 = 18,874,368
    short* Wob   = (short*)(ws + 37748736);   // 2304x2048 bf16 =  9,437,184
    short* QKVb  = (short*)(ws + 47185920);   // 4096x4096 bf16 = 33,554,432
    short* Vt    = (short*)(ws + 80740352);   // 1024x4096 bf16 =  8,388,608  (end 89,128,960)
    _Float16* Opart = (_Float16*)(ws + 0);    // 2 x 16 MB fp16 partials
    float*    Psp   = (float*)(ws + 33554432);
    short*    Ob    = (short*)(ws + 0);

    cast_f32_bf16<<<9216, 256, 0, stream>>>(X,  Xb,  2359296);
    cast_wqkv<<<9216, 256, 0, stream>>>(Wq, Wk, Wv, Wqkvb);
    cast_f32_bf16<<<4608, 256, 0, stream>>>(Wo, Wob, 1179648);

    gemm_qkv<<<dim3(32,32), 256, 0, stream>>>(Xb, Wqkvb, QKVb, Vt);

    rope_kernel<<<24576, 256, 0, stream>>>(QKVb, pos);

    attn_kernel<<<512, 256, 0, stream>>>(QKVb, Vt, Opart, Psp);

    combine_kernel<<<4096, 256, 0, stream>>>(Opart, Opart + (size_t)4096*2048, Psp, Ob);

    gemm_lds<2><<<dim3(18,32), 256, 0, stream>>>(Ob, Wob, out, 4096, 2304, 2048, 2304);
}